// Round 1
// baseline (397.076 us; speedup 1.0000x reference)
//
#include <hip/hip_runtime.h>
#include <stdint.h>

// Problem constants
#define BATCH 8
#define TT    2048
#define CC    1024
#define GG    2
#define EE    320
#define KN    (GG * EE)   // 640
#define DD    256
#define MTOT  (BATCH * TT) // 16384

// GEMM tiling
#define BM 128
#define BN 64
#define BK 32
#define LDA (BM + 4)
#define LDB (BN + 4)

__device__ __forceinline__ unsigned int f32_orderable(float x) {
    unsigned int b = __float_as_uint(x);
    return (b & 0x80000000u) ? ~b : (b | 0x80000000u);
}

__global__ void init_slots_kernel(unsigned long long* __restrict__ slots) {
    if (threadIdx.x < 16) slots[threadIdx.x] = 0ull;
}

// C = X (16384x1024) * W^T (1024x640), consumed only by a per-(b,half) argmax.
// slots[r], r = m/1024, holds max of packed (orderable(val)<<32 | ~c),
// c = (m%1024)*640 + k  -> on value ties, smaller c wins (jnp.argmax first-match).
__global__ __launch_bounds__(128)
void gemm_argmax_kernel(const float* __restrict__ X, const float* __restrict__ W,
                        const float* __restrict__ bias,
                        unsigned long long* __restrict__ slots) {
    __shared__ float As[BK][LDA];   // k-major, padded (+4 keeps b128 reads aligned, banks 2-way)
    __shared__ float Bs[BK][LDB];

    const int tid = threadIdx.x;
    const int bn = blockIdx.x;      // 0..9   (fastest: W tile L2-resident, X tile read 10x concurrently)
    const int bm = blockIdx.y;      // 0..127
    const int m0 = bm * BM;
    const int n0 = bn * BN;

    const int tx = tid & 7;         // col group: cols tx*8 .. tx*8+7
    const int ty = tid >> 3;        // row group: rows ty*8 .. ty*8+7

    float acc[8][8];
#pragma unroll
    for (int i = 0; i < 8; i++)
#pragma unroll
        for (int j = 0; j < 8; j++) acc[i][j] = 0.0f;

    const int lm = tid >> 3;        // 0..15
    const int lk = (tid & 7) * 4;   // 0,4,...,28

    const float* Xb = X + (size_t)m0 * CC;
    const float* Wb = W + (size_t)n0 * CC;

    for (int k0 = 0; k0 < CC; k0 += BK) {
        // Stage A tile: 128 rows x 32 k, transposed to k-major
#pragma unroll
        for (int r = 0; r < 8; r++) {
            int m = r * 16 + lm;
            float4 v = *(const float4*)(Xb + (size_t)m * CC + k0 + lk);
            As[lk + 0][m] = v.x; As[lk + 1][m] = v.y;
            As[lk + 2][m] = v.z; As[lk + 3][m] = v.w;
        }
        // Stage B tile: 64 rows x 32 k
#pragma unroll
        for (int r = 0; r < 4; r++) {
            int m = r * 16 + lm;
            float4 v = *(const float4*)(Wb + (size_t)m * CC + k0 + lk);
            Bs[lk + 0][m] = v.x; Bs[lk + 1][m] = v.y;
            Bs[lk + 2][m] = v.z; Bs[lk + 3][m] = v.w;
        }
        __syncthreads();

#pragma unroll
        for (int kk = 0; kk < BK; kk++) {
            float4 a0 = *(const float4*)&As[kk][ty * 8];
            float4 a1 = *(const float4*)&As[kk][ty * 8 + 4];
            float4 b0 = *(const float4*)&Bs[kk][tx * 8];
            float4 b1 = *(const float4*)&Bs[kk][tx * 8 + 4];
            float a[8] = {a0.x, a0.y, a0.z, a0.w, a1.x, a1.y, a1.z, a1.w};
            float b[8] = {b0.x, b0.y, b0.z, b0.w, b1.x, b1.y, b1.z, b1.w};
#pragma unroll
            for (int i = 0; i < 8; i++)
#pragma unroll
                for (int j = 0; j < 8; j++)
                    acc[i][j] = fmaf(a[i], b[j], acc[i][j]);
        }
        __syncthreads();
    }

    // Per-thread packed argmax (bias added here; it's zeros in the data but faithful)
    unsigned long long best = 0ull;
#pragma unroll
    for (int i = 0; i < 8; i++) {
        int mg = m0 + ty * 8 + i;
        int tl = mg & 1023;              // t within half
#pragma unroll
        for (int j = 0; j < 8; j++) {
            int kg = n0 + tx * 8 + j;
            float v = acc[i][j] + bias[kg];
            unsigned int c = (unsigned int)(tl * KN + kg);
            unsigned long long p =
                ((unsigned long long)f32_orderable(v) << 32) |
                (unsigned long long)(~c);
            if (p > best) best = p;
        }
    }

    // Wave reduce (64 lanes), then 2-wave block reduce, one atomic per block
#pragma unroll
    for (int off = 32; off > 0; off >>= 1) {
        unsigned long long o = __shfl_down(best, off, 64);
        if (o > best) best = o;
    }
    __shared__ unsigned long long red[2];
    if ((tid & 63) == 0) red[tid >> 6] = best;
    __syncthreads();
    if (tid == 0) {
        unsigned long long b0 = red[0], b1 = red[1];
        unsigned long long m = b0 > b1 ? b0 : b1;
        atomicMax(slots + (m0 >> 10), m);   // slot r = m0/1024 (BM=128 divides 1024)
    }
}

__global__ void zero_out_kernel(float4* __restrict__ out, int n4) {
    int i = blockIdx.x * blockDim.x + threadIdx.x;
    int stride = gridDim.x * blockDim.x;
    for (; i < n4; i += stride) out[i] = make_float4(0.f, 0.f, 0.f, 0.f);
}

// 16 blocks x 256 threads: decode slot r -> (t*, k*), write codebook row.
__global__ void scatter_kernel(const unsigned long long* __restrict__ slots,
                               const float* __restrict__ codebook,
                               float* __restrict__ out) {
    int r = blockIdx.x;                       // 0..15 = 2b + h
    unsigned long long p = slots[r];
    unsigned int c = ~(unsigned int)(p & 0xFFFFFFFFull);
    int tl = (int)(c / KN);
    int kg = (int)(c % KN);
    int b = r >> 1, h = r & 1;
    int n = b * TT + h * 1024 + tl;           // = b*2048 + t*
    int g = kg / EE;
    out[(size_t)n * 512 + (size_t)g * DD + threadIdx.x] =
        codebook[(size_t)kg * DD + threadIdx.x];
}

extern "C" void kernel_launch(void* const* d_in, const int* in_sizes, int n_in,
                              void* d_out, int out_size, void* d_ws, size_t ws_size,
                              hipStream_t stream) {
    const float* X        = (const float*)d_in[0];  // (8,2048,1024)
    const float* W        = (const float*)d_in[1];  // (640,1024)
    const float* bias     = (const float*)d_in[2];  // (640,)
    const float* codebook = (const float*)d_in[3];  // (640,256)
    float* out = (float*)d_out;                     // (8,2048,512) fp32
    unsigned long long* slots = (unsigned long long*)d_ws;  // 16 slots

    hipLaunchKernelGGL(init_slots_kernel, dim3(1), dim3(64), 0, stream, slots);

    dim3 ggrid(KN / BN, MTOT / BM);   // (10, 128)
    hipLaunchKernelGGL(gemm_argmax_kernel, ggrid, dim3(128), 0, stream,
                       X, W, bias, slots);

    int n4 = out_size / 4;            // 2,097,152 float4
    hipLaunchKernelGGL(zero_out_kernel, dim3(2048), dim3(256), 0, stream,
                       (float4*)d_out, n4);

    hipLaunchKernelGGL(scatter_kernel, dim3(16), dim3(256), 0, stream,
                       slots, codebook, out);
}

// Round 2
// 259.501 us; speedup vs baseline: 1.5302x; 1.5302x over previous
//
#include <hip/hip_runtime.h>
#include <stdint.h>

// Problem constants
#define BATCH 8
#define TT    2048
#define CC    1024
#define GG    2
#define EE    320
#define KN    (GG * EE)    // 640
#define DD    256
#define MTOT  (BATCH * TT) // 16384
#define K2    2048         // stored split-K: [hi(0:1024) | lo(1024:2048)]

typedef __attribute__((ext_vector_type(8))) short short8;
typedef __attribute__((ext_vector_type(4))) float f32x4;

__device__ __forceinline__ unsigned int f32_orderable(float x) {
    unsigned int b = __float_as_uint(x);
    return (b & 0x80000000u) ? ~b : (b | 0x80000000u);
}

__device__ __forceinline__ unsigned short bf16_rne(float x) {
    unsigned int u = __float_as_uint(x);
    return (unsigned short)((u + 0x7FFFu + ((u >> 16) & 1u)) >> 16);
}

__global__ void init_slots_kernel(unsigned long long* __restrict__ slots) {
    if (threadIdx.x < 16) slots[threadIdx.x] = 0ull;
}

// fp32 (rows x 1024) -> bf16 hi/lo split, row-major rows x 2048: [hi | lo]
__global__ __launch_bounds__(256)
void convert_split_kernel(const float* __restrict__ src, unsigned short* __restrict__ dst,
                          int n_i4) {
    int i4 = blockIdx.x * blockDim.x + threadIdx.x;
    if (i4 >= n_i4) return;
    int m = i4 >> 8;             // 256 float4 per 1024-row
    int k = (i4 & 255) * 4;
    float4 v = ((const float4*)src)[i4];
    ushort4 hi, lo;
    hi.x = bf16_rne(v.x); lo.x = bf16_rne(v.x - __uint_as_float((unsigned)hi.x << 16));
    hi.y = bf16_rne(v.y); lo.y = bf16_rne(v.y - __uint_as_float((unsigned)hi.y << 16));
    hi.z = bf16_rne(v.z); lo.z = bf16_rne(v.z - __uint_as_float((unsigned)hi.z << 16));
    hi.w = bf16_rne(v.w); lo.w = bf16_rne(v.w - __uint_as_float((unsigned)hi.w << 16));
    *(ushort4*)(dst + (size_t)m * K2 + k)        = hi;
    *(ushort4*)(dst + (size_t)m * K2 + 1024 + k) = lo;
}

__device__ __forceinline__ void gload_lds16(const void* g, void* l) {
    __builtin_amdgcn_global_load_lds(
        (const __attribute__((address_space(1))) unsigned int*)g,
        (__attribute__((address_space(3))) unsigned int*)l,
        16, 0, 0);
}

// ------------------- MFMA path -------------------
// C = A2(16384x[hi|lo]) x B2(640x[hi|lo])^T over 3 passes (hi*hi + lo*hi + hi*lo),
// consumed only by per-(m/1024) packed argmax.
__global__ __launch_bounds__(256)
void gemm_argmax_mfma(const unsigned short* __restrict__ A2,
                      const unsigned short* __restrict__ B2,
                      const float* __restrict__ bias,
                      unsigned long long* __restrict__ slots) {
    __shared__ unsigned short As[128 * 32];  // row-major, 64B per row (UNPADDED: global_load_lds lane order)
    __shared__ unsigned short Bs[128 * 32];
    __shared__ unsigned long long red[4];

    const int tid  = threadIdx.x;
    const int lane = tid & 63;
    const int wave = tid >> 6;
    const int m0 = blockIdx.y * 128;
    const int n0 = blockIdx.x * 128;
    const int wm = (wave >> 1) * 64;   // wave's 64x64 region within 128x128
    const int wn = (wave & 1) * 64;

    f32x4 acc[4][4] = {};

    // staging: lane l covers row (l>>2), bytes (l&3)*16 within a 16-row x 64B chunk
    const int srow = lane >> 2;
    const int scol = (lane & 3) * 16;
    // fragment read: row (lane&15), k-bytes (lane>>4)*16
    const int fr = lane & 15;
    const int fk = (lane >> 4) * 16;

    for (int kp = 0; kp < 3; kp++) {
        const int aoff = (kp == 1) ? 1024 : 0;
        const int boff = (kp == 2) ? 1024 : 0;
        const unsigned short* Ab = A2 + (size_t)m0 * K2 + aoff;
        const unsigned short* Bb = B2 + (size_t)n0 * K2 + boff;
        for (int k0 = 0; k0 < 1024; k0 += 32) {
            // ---- async stage 128x32 A and 128x32 B (each wave: 2+2 chunks of 16 rows) ----
#pragma unroll
            for (int i = 0; i < 2; i++) {
                int rbase = wave * 32 + i * 16;
                const char* ga = (const char*)(Ab + (size_t)(rbase + srow) * K2 + k0) + scol;
                gload_lds16(ga, (char*)As + rbase * 64);
                const char* gb = (const char*)(Bb + (size_t)(rbase + srow) * K2 + k0) + scol;
                gload_lds16(gb, (char*)Bs + rbase * 64);
            }
            __syncthreads();   // drains vmcnt -> staging visible

            short8 afrag[4], bfrag[4];
#pragma unroll
            for (int t = 0; t < 4; t++) {
                afrag[t] = *(const short8*)((const char*)As + (wm + t * 16 + fr) * 64 + fk);
                bfrag[t] = *(const short8*)((const char*)Bs + (wn + t * 16 + fr) * 64 + fk);
            }
#pragma unroll
            for (int ti = 0; ti < 4; ti++)
#pragma unroll
                for (int tj = 0; tj < 4; tj++)
                    acc[ti][tj] = __builtin_amdgcn_mfma_f32_16x16x32_bf16(
                        afrag[ti], bfrag[tj], acc[ti][tj], 0, 0, 0);
            __syncthreads();   // protect LDS from next stage's overwrite
        }
    }

    // ---- fused argmax epilogue ----
    // C/D layout (16x16x32): col = lane&15, row = (lane>>4)*4 + reg
    float bias4[4];
#pragma unroll
    for (int tj = 0; tj < 4; tj++) bias4[tj] = bias[n0 + wn + tj * 16 + (lane & 15)];

    unsigned long long best = 0ull;
#pragma unroll
    for (int ti = 0; ti < 4; ti++) {
#pragma unroll
        for (int r = 0; r < 4; r++) {
            int m  = m0 + wm + ti * 16 + (lane >> 4) * 4 + r;
            int tl = m & 1023;
#pragma unroll
            for (int tj = 0; tj < 4; tj++) {
                int n = n0 + wn + tj * 16 + (lane & 15);
                float v = acc[ti][tj][r] + bias4[tj];
                unsigned int c = (unsigned int)(tl * KN + n);
                unsigned long long p =
                    ((unsigned long long)f32_orderable(v) << 32) |
                    (unsigned long long)(~c);
                if (p > best) best = p;
            }
        }
    }
#pragma unroll
    for (int off = 32; off > 0; off >>= 1) {
        unsigned long long o = __shfl_down(best, off, 64);
        if (o > best) best = o;
    }
    if (lane == 0) red[wave] = best;
    __syncthreads();
    if (tid == 0) {
        unsigned long long b = red[0];
        for (int w = 1; w < 4; w++) if (red[w] > b) b = red[w];
        atomicMax(slots + (m0 >> 10), b);
    }
}

// ------------------- fp32 fallback path (round-1 kernel, used if ws too small) -------------------
#define BM 128
#define BN 64
#define BK 32
#define LDA (BM + 4)
#define LDB (BN + 4)

__global__ __launch_bounds__(128)
void gemm_argmax_f32(const float* __restrict__ X, const float* __restrict__ W,
                     const float* __restrict__ bias,
                     unsigned long long* __restrict__ slots) {
    __shared__ float As[BK][LDA];
    __shared__ float Bs[BK][LDB];
    const int tid = threadIdx.x;
    const int m0 = blockIdx.y * BM;
    const int n0 = blockIdx.x * BN;
    const int tx = tid & 7, ty = tid >> 3;
    float acc[8][8];
#pragma unroll
    for (int i = 0; i < 8; i++)
#pragma unroll
        for (int j = 0; j < 8; j++) acc[i][j] = 0.0f;
    const int lm = tid >> 3, lk = (tid & 7) * 4;
    const float* Xb = X + (size_t)m0 * CC;
    const float* Wb = W + (size_t)n0 * CC;
    for (int k0 = 0; k0 < CC; k0 += BK) {
#pragma unroll
        for (int r = 0; r < 8; r++) {
            int m = r * 16 + lm;
            float4 v = *(const float4*)(Xb + (size_t)m * CC + k0 + lk);
            As[lk + 0][m] = v.x; As[lk + 1][m] = v.y; As[lk + 2][m] = v.z; As[lk + 3][m] = v.w;
        }
#pragma unroll
        for (int r = 0; r < 4; r++) {
            int m = r * 16 + lm;
            float4 v = *(const float4*)(Wb + (size_t)m * CC + k0 + lk);
            Bs[lk + 0][m] = v.x; Bs[lk + 1][m] = v.y; Bs[lk + 2][m] = v.z; Bs[lk + 3][m] = v.w;
        }
        __syncthreads();
#pragma unroll
        for (int kk = 0; kk < BK; kk++) {
            float4 a0 = *(const float4*)&As[kk][ty * 8];
            float4 a1 = *(const float4*)&As[kk][ty * 8 + 4];
            float4 b0 = *(const float4*)&Bs[kk][tx * 8];
            float4 b1 = *(const float4*)&Bs[kk][tx * 8 + 4];
            float a[8] = {a0.x, a0.y, a0.z, a0.w, a1.x, a1.y, a1.z, a1.w};
            float b[8] = {b0.x, b0.y, b0.z, b0.w, b1.x, b1.y, b1.z, b1.w};
#pragma unroll
            for (int i = 0; i < 8; i++)
#pragma unroll
                for (int j = 0; j < 8; j++) acc[i][j] = fmaf(a[i], b[j], acc[i][j]);
        }
        __syncthreads();
    }
    unsigned long long best = 0ull;
#pragma unroll
    for (int i = 0; i < 8; i++) {
        int mg = m0 + ty * 8 + i;
        int tl = mg & 1023;
#pragma unroll
        for (int j = 0; j < 8; j++) {
            int kg = n0 + tx * 8 + j;
            float v = acc[i][j] + bias[kg];
            unsigned int c = (unsigned int)(tl * KN + kg);
            unsigned long long p = ((unsigned long long)f32_orderable(v) << 32) |
                                   (unsigned long long)(~c);
            if (p > best) best = p;
        }
    }
#pragma unroll
    for (int off = 32; off > 0; off >>= 1) {
        unsigned long long o = __shfl_down(best, off, 64);
        if (o > best) best = o;
    }
    __shared__ unsigned long long red2[2];
    if ((tid & 63) == 0) red2[tid >> 6] = best;
    __syncthreads();
    if (tid == 0) {
        unsigned long long b0 = red2[0], b1 = red2[1];
        atomicMax(slots + (m0 >> 10), b0 > b1 ? b0 : b1);
    }
}

__global__ void zero_out_kernel(float4* __restrict__ out, int n4) {
    int i = blockIdx.x * blockDim.x + threadIdx.x;
    int stride = gridDim.x * blockDim.x;
    for (; i < n4; i += stride) out[i] = make_float4(0.f, 0.f, 0.f, 0.f);
}

__global__ void scatter_kernel(const unsigned long long* __restrict__ slots,
                               const float* __restrict__ codebook,
                               float* __restrict__ out) {
    int r = blockIdx.x;
    unsigned long long p = slots[r];
    unsigned int c = ~(unsigned int)(p & 0xFFFFFFFFull);
    int tl = (int)(c / KN);
    int kg = (int)(c % KN);
    int b = r >> 1, h = r & 1;
    int n = b * TT + h * 1024 + tl;
    int g = kg / EE;
    out[(size_t)n * 512 + (size_t)g * DD + threadIdx.x] =
        codebook[(size_t)kg * DD + threadIdx.x];
}

extern "C" void kernel_launch(void* const* d_in, const int* in_sizes, int n_in,
                              void* d_out, int out_size, void* d_ws, size_t ws_size,
                              hipStream_t stream) {
    const float* X        = (const float*)d_in[0];  // (8,2048,1024)
    const float* W        = (const float*)d_in[1];  // (640,1024)
    const float* bias     = (const float*)d_in[2];  // (640,)
    const float* codebook = (const float*)d_in[3];  // (640,256)
    float* out = (float*)d_out;                     // (8,2048,512) fp32

    unsigned long long* slots = (unsigned long long*)d_ws;
    const size_t A2_off = 256;
    const size_t A2_bytes = (size_t)MTOT * K2 * 2;       // 67,108,864
    const size_t B2_off = A2_off + A2_bytes;
    const size_t B2_bytes = (size_t)KN * K2 * 2;         // 2,621,440
    const size_t need = B2_off + B2_bytes;

    hipLaunchKernelGGL(init_slots_kernel, dim3(1), dim3(64), 0, stream, slots);

    if (ws_size >= need) {
        unsigned short* A2 = (unsigned short*)((char*)d_ws + A2_off);
        unsigned short* B2 = (unsigned short*)((char*)d_ws + B2_off);
        int nx = MTOT * CC / 4;   // 4,194,304
        int nw = KN * CC / 4;     // 163,840
        hipLaunchKernelGGL(convert_split_kernel, dim3(nx / 256), dim3(256), 0, stream,
                           X, A2, nx);
        hipLaunchKernelGGL(convert_split_kernel, dim3(nw / 256), dim3(256), 0, stream,
                           W, B2, nw);
        hipLaunchKernelGGL(gemm_argmax_mfma, dim3(KN / 128, MTOT / 128), dim3(256), 0, stream,
                           A2, B2, bias, slots);
    } else {
        hipLaunchKernelGGL(gemm_argmax_f32, dim3(KN / BN, MTOT / BM), dim3(128), 0, stream,
                           X, W, bias, slots);
    }

    int n4 = out_size / 4;
    hipLaunchKernelGGL(zero_out_kernel, dim3(4096), dim3(256), 0, stream,
                       (float4*)d_out, n4);
    hipLaunchKernelGGL(scatter_kernel, dim3(16), dim3(256), 0, stream,
                       slots, codebook, out);
}

// Round 3
// 210.055 us; speedup vs baseline: 1.8903x; 1.2354x over previous
//
#include <hip/hip_runtime.h>
#include <stdint.h>

// Problem constants
#define BATCH 8
#define TT    2048
#define CC    1024
#define GG    2
#define EE    320
#define KN    (GG * EE)    // 640
#define DD    256
#define MTOT  (BATCH * TT) // 16384
#define K2    2048         // stored split-K per row: [hi(0:1024) | lo(1024:2048)]

typedef __attribute__((ext_vector_type(8))) short short8;
typedef __attribute__((ext_vector_type(4))) float f32x4;

__device__ __forceinline__ unsigned int f32_orderable(float x) {
    unsigned int b = __float_as_uint(x);
    return (b & 0x80000000u) ? ~b : (b | 0x80000000u);
}

__device__ __forceinline__ unsigned short bf16_rne(float x) {
    unsigned int u = __float_as_uint(x);
    return (unsigned short)((u + 0x7FFFu + ((u >> 16) & 1u)) >> 16);
}

__global__ void init_slots_kernel(unsigned long long* __restrict__ slots) {
    if (threadIdx.x < 16) slots[threadIdx.x] = 0ull;
}

// fp32 (rows x 1024) -> bf16 hi/lo split, row-major rows x 2048: [hi | lo].
// Also zero-inits the 16 argmax slots (init_slots=1 for the X conversion).
__global__ __launch_bounds__(256)
void convert_split_kernel(const float* __restrict__ src, unsigned short* __restrict__ dst,
                          int n_i4, unsigned long long* __restrict__ slots, int init_slots) {
    int i4 = blockIdx.x * blockDim.x + threadIdx.x;
    if (init_slots && blockIdx.x == 0 && threadIdx.x < 16) slots[threadIdx.x] = 0ull;
    if (i4 >= n_i4) return;
    int m = i4 >> 8;             // 256 float4 per 1024-row
    int k = (i4 & 255) * 4;
    float4 v = ((const float4*)src)[i4];
    ushort4 hi, lo;
    hi.x = bf16_rne(v.x); lo.x = bf16_rne(v.x - __uint_as_float((unsigned)hi.x << 16));
    hi.y = bf16_rne(v.y); lo.y = bf16_rne(v.y - __uint_as_float((unsigned)hi.y << 16));
    hi.z = bf16_rne(v.z); lo.z = bf16_rne(v.z - __uint_as_float((unsigned)hi.z << 16));
    hi.w = bf16_rne(v.w); lo.w = bf16_rne(v.w - __uint_as_float((unsigned)hi.w << 16));
    *(ushort4*)(dst + (size_t)m * K2 + k)        = hi;
    *(ushort4*)(dst + (size_t)m * K2 + 1024 + k) = lo;
}

__device__ __forceinline__ void gload_lds16(const void* g, void* l) {
    __builtin_amdgcn_global_load_lds(
        (const __attribute__((address_space(1))) unsigned int*)g,
        (__attribute__((address_space(3))) unsigned int*)l,
        16, 0, 0);
}

// ------------------- MFMA path -------------------
// C = A x B^T via split-bf16: hi*hi + lo*hi + hi*lo, FUSED in one K-loop
// (48 MFMA per wave per barrier-pair). Consumed only by per-(m/1024) argmax.
// Grid: 640 blocks, XCD-swizzled so the 5 n-tiles of one m-tile run on one XCD.
__global__ __launch_bounds__(256)
void gemm_argmax_mfma(const unsigned short* __restrict__ A2,
                      const unsigned short* __restrict__ B2,
                      const float* __restrict__ bias,
                      unsigned long long* __restrict__ slots) {
    __shared__ unsigned short As_h[128 * 32];  // row-major, 64B/row (UNPADDED: global_load_lds lane order)
    __shared__ unsigned short As_l[128 * 32];
    __shared__ unsigned short Bs_h[128 * 32];
    __shared__ unsigned short Bs_l[128 * 32];
    __shared__ unsigned long long red[4];

    const int tid  = threadIdx.x;
    const int lane = tid & 63;
    const int wave = tid >> 6;

    // XCD swizzle: blocks on one XCD cover 16 m-tiles x all 5 n-tiles,
    // n-fastest -> A-tile re-reads hit that XCD's L2.
    const int l   = blockIdx.x;        // 0..639
    const int xcd = l & 7;
    const int w   = l >> 3;            // 0..79
    const int mt  = xcd * 16 + w / 5;  // 0..127
    const int nt  = w % 5;             // 0..4
    const int m0 = mt * 128;
    const int n0 = nt * 128;

    const int wm = (wave >> 1) * 64;   // wave's 64x64 region within 128x128
    const int wn = (wave & 1) * 64;

    f32x4 acc[4][4] = {};

    // staging: lane covers row (lane>>2), bytes (lane&3)*16 within a 16-row x 64B chunk
    const int srow = lane >> 2;
    const int scol = (lane & 3) * 16;
    // fragment read: row (lane&15), k-bytes (lane>>4)*16
    const int fr = lane & 15;
    const int fk = (lane >> 4) * 16;

    const unsigned short* Ab = A2 + (size_t)m0 * K2;
    const unsigned short* Bb = B2 + (size_t)n0 * K2;

    for (int k0 = 0; k0 < 1024; k0 += 32) {
        // ---- async stage 4 tiles of 128x32 (each wave: 2 chunks x 4 tiles) ----
#pragma unroll
        for (int i = 0; i < 2; i++) {
            int rbase = wave * 32 + i * 16;
            int r = rbase + srow;
            const char* ar = (const char*)(Ab + (size_t)r * K2 + k0) + scol;
            const char* br = (const char*)(Bb + (size_t)r * K2 + k0) + scol;
            gload_lds16(ar,        (char*)As_h + rbase * 64);
            gload_lds16(ar + 2048, (char*)As_l + rbase * 64);   // +1024 shorts
            gload_lds16(br,        (char*)Bs_h + rbase * 64);
            gload_lds16(br + 2048, (char*)Bs_l + rbase * 64);
        }
        __syncthreads();   // drains vmcnt -> staging visible

        short8 ah[4], al[4], bh[4], bl[4];
#pragma unroll
        for (int t = 0; t < 4; t++) {
            ah[t] = *(const short8*)((const char*)As_h + (wm + t * 16 + fr) * 64 + fk);
            al[t] = *(const short8*)((const char*)As_l + (wm + t * 16 + fr) * 64 + fk);
            bh[t] = *(const short8*)((const char*)Bs_h + (wn + t * 16 + fr) * 64 + fk);
            bl[t] = *(const short8*)((const char*)Bs_l + (wn + t * 16 + fr) * 64 + fk);
        }
#pragma unroll
        for (int ti = 0; ti < 4; ti++)
#pragma unroll
            for (int tj = 0; tj < 4; tj++)
                acc[ti][tj] = __builtin_amdgcn_mfma_f32_16x16x32_bf16(ah[ti], bh[tj], acc[ti][tj], 0, 0, 0);
#pragma unroll
        for (int ti = 0; ti < 4; ti++)
#pragma unroll
            for (int tj = 0; tj < 4; tj++)
                acc[ti][tj] = __builtin_amdgcn_mfma_f32_16x16x32_bf16(al[ti], bh[tj], acc[ti][tj], 0, 0, 0);
#pragma unroll
        for (int ti = 0; ti < 4; ti++)
#pragma unroll
            for (int tj = 0; tj < 4; tj++)
                acc[ti][tj] = __builtin_amdgcn_mfma_f32_16x16x32_bf16(ah[ti], bl[tj], acc[ti][tj], 0, 0, 0);
        __syncthreads();   // protect LDS from next stage's overwrite
    }

    // ---- fused argmax epilogue ----
    // C/D layout (16x16x32): col = lane&15, row = (lane>>4)*4 + reg
    float bias4[4];
#pragma unroll
    for (int tj = 0; tj < 4; tj++) bias4[tj] = bias[n0 + wn + tj * 16 + (lane & 15)];

    unsigned long long best = 0ull;
#pragma unroll
    for (int ti = 0; ti < 4; ti++) {
#pragma unroll
        for (int r = 0; r < 4; r++) {
            int m  = m0 + wm + ti * 16 + (lane >> 4) * 4 + r;
            int tl = m & 1023;
#pragma unroll
            for (int tj = 0; tj < 4; tj++) {
                int n = n0 + wn + tj * 16 + (lane & 15);
                float v = acc[ti][tj][r] + bias4[tj];
                unsigned int c = (unsigned int)(tl * KN + n);
                unsigned long long p =
                    ((unsigned long long)f32_orderable(v) << 32) |
                    (unsigned long long)(~c);
                if (p > best) best = p;
            }
        }
    }
#pragma unroll
    for (int off = 32; off > 0; off >>= 1) {
        unsigned long long o = __shfl_down(best, off, 64);
        if (o > best) best = o;
    }
    if (lane == 0) red[wave] = best;
    __syncthreads();
    if (tid == 0) {
        unsigned long long b = red[0];
        for (int wv = 1; wv < 4; wv++) if (red[wv] > b) b = red[wv];
        atomicMax(slots + (m0 >> 10), b);
    }
}

// ------------------- fp32 fallback path (round-1 kernel, used if ws too small) -------------------
#define BM 128
#define BN 64
#define BK 32
#define LDA (BM + 4)
#define LDB (BN + 4)

__global__ __launch_bounds__(128)
void gemm_argmax_f32(const float* __restrict__ X, const float* __restrict__ W,
                     const float* __restrict__ bias,
                     unsigned long long* __restrict__ slots) {
    __shared__ float As[BK][LDA];
    __shared__ float Bs[BK][LDB];
    const int tid = threadIdx.x;
    const int m0 = blockIdx.y * BM;
    const int n0 = blockIdx.x * BN;
    const int tx = tid & 7, ty = tid >> 3;
    float acc[8][8];
#pragma unroll
    for (int i = 0; i < 8; i++)
#pragma unroll
        for (int j = 0; j < 8; j++) acc[i][j] = 0.0f;
    const int lm = tid >> 3, lk = (tid & 7) * 4;
    const float* Xb = X + (size_t)m0 * CC;
    const float* Wb = W + (size_t)n0 * CC;
    for (int k0 = 0; k0 < CC; k0 += BK) {
#pragma unroll
        for (int r = 0; r < 8; r++) {
            int m = r * 16 + lm;
            float4 v = *(const float4*)(Xb + (size_t)m * CC + k0 + lk);
            As[lk + 0][m] = v.x; As[lk + 1][m] = v.y; As[lk + 2][m] = v.z; As[lk + 3][m] = v.w;
        }
#pragma unroll
        for (int r = 0; r < 4; r++) {
            int m = r * 16 + lm;
            float4 v = *(const float4*)(Wb + (size_t)m * CC + k0 + lk);
            Bs[lk + 0][m] = v.x; Bs[lk + 1][m] = v.y; Bs[lk + 2][m] = v.z; Bs[lk + 3][m] = v.w;
        }
        __syncthreads();
#pragma unroll
        for (int kk = 0; kk < BK; kk++) {
            float4 a0 = *(const float4*)&As[kk][ty * 8];
            float4 a1 = *(const float4*)&As[kk][ty * 8 + 4];
            float4 b0 = *(const float4*)&Bs[kk][tx * 8];
            float4 b1 = *(const float4*)&Bs[kk][tx * 8 + 4];
            float a[8] = {a0.x, a0.y, a0.z, a0.w, a1.x, a1.y, a1.z, a1.w};
            float b[8] = {b0.x, b0.y, b0.z, b0.w, b1.x, b1.y, b1.z, b1.w};
#pragma unroll
            for (int i = 0; i < 8; i++)
#pragma unroll
                for (int j = 0; j < 8; j++) acc[i][j] = fmaf(a[i], b[j], acc[i][j]);
        }
        __syncthreads();
    }
    unsigned long long best = 0ull;
#pragma unroll
    for (int i = 0; i < 8; i++) {
        int mg = m0 + ty * 8 + i;
        int tl = mg & 1023;
#pragma unroll
        for (int j = 0; j < 8; j++) {
            int kg = n0 + tx * 8 + j;
            float v = acc[i][j] + bias[kg];
            unsigned int c = (unsigned int)(tl * KN + kg);
            unsigned long long p = ((unsigned long long)f32_orderable(v) << 32) |
                                   (unsigned long long)(~c);
            if (p > best) best = p;
        }
    }
#pragma unroll
    for (int off = 32; off > 0; off >>= 1) {
        unsigned long long o = __shfl_down(best, off, 64);
        if (o > best) best = o;
    }
    __shared__ unsigned long long red2[2];
    if ((tid & 63) == 0) red2[tid >> 6] = best;
    __syncthreads();
    if (tid == 0) {
        unsigned long long b0 = red2[0], b1 = red2[1];
        atomicMax(slots + (m0 >> 10), b0 > b1 ? b0 : b1);
    }
}

__global__ void zero_out_kernel(float4* __restrict__ out, int n4) {
    int i = blockIdx.x * blockDim.x + threadIdx.x;
    int stride = gridDim.x * blockDim.x;
    for (; i < n4; i += stride) out[i] = make_float4(0.f, 0.f, 0.f, 0.f);
}

__global__ void scatter_kernel(const unsigned long long* __restrict__ slots,
                               const float* __restrict__ codebook,
                               float* __restrict__ out) {
    int r = blockIdx.x;
    unsigned long long p = slots[r];
    unsigned int c = ~(unsigned int)(p & 0xFFFFFFFFull);
    int tl = (int)(c / KN);
    int kg = (int)(c % KN);
    int b = r >> 1, h = r & 1;
    int n = b * TT + h * 1024 + tl;
    int g = kg / EE;
    out[(size_t)n * 512 + (size_t)g * DD + threadIdx.x] =
        codebook[(size_t)kg * DD + threadIdx.x];
}

extern "C" void kernel_launch(void* const* d_in, const int* in_sizes, int n_in,
                              void* d_out, int out_size, void* d_ws, size_t ws_size,
                              hipStream_t stream) {
    const float* X        = (const float*)d_in[0];  // (8,2048,1024)
    const float* W        = (const float*)d_in[1];  // (640,1024)
    const float* bias     = (const float*)d_in[2];  // (640,)
    const float* codebook = (const float*)d_in[3];  // (640,256)
    float* out = (float*)d_out;                     // (8,2048,512) fp32

    unsigned long long* slots = (unsigned long long*)d_ws;
    const size_t A2_off = 256;
    const size_t A2_bytes = (size_t)MTOT * K2 * 2;       // 67,108,864
    const size_t B2_off = A2_off + A2_bytes;
    const size_t B2_bytes = (size_t)KN * K2 * 2;         // 2,621,440
    const size_t need = B2_off + B2_bytes;

    if (ws_size >= need) {
        unsigned short* A2 = (unsigned short*)((char*)d_ws + A2_off);
        unsigned short* B2 = (unsigned short*)((char*)d_ws + B2_off);
        int nx = MTOT * CC / 4;   // 4,194,304
        int nw = KN * CC / 4;     // 163,840
        hipLaunchKernelGGL(convert_split_kernel, dim3(nx / 256), dim3(256), 0, stream,
                           X, A2, nx, slots, 1);
        hipLaunchKernelGGL(convert_split_kernel, dim3(nw / 256), dim3(256), 0, stream,
                           W, B2, nw, slots, 0);
        hipLaunchKernelGGL(gemm_argmax_mfma, dim3(640), dim3(256), 0, stream,
                           A2, B2, bias, slots);
    } else {
        hipLaunchKernelGGL(init_slots_kernel, dim3(1), dim3(64), 0, stream, slots);
        hipLaunchKernelGGL(gemm_argmax_f32, dim3(KN / BN, MTOT / BM), dim3(128), 0, stream,
                           X, W, bias, slots);
    }

    int n4 = out_size / 4;
    hipLaunchKernelGGL(zero_out_kernel, dim3(4096), dim3(256), 0, stream,
                       (float4*)d_out, n4);
    hipLaunchKernelGGL(scatter_kernel, dim3(16), dim3(256), 0, stream,
                       slots, codebook, out);
}